// Round 1
// baseline (472.376 us; speedup 1.0000x reference)
//
#include <hip/hip_runtime.h>
#include <cstdint>

typedef float  f32x4 __attribute__((ext_vector_type(4)));
typedef short  s16x8 __attribute__((ext_vector_type(8)));
typedef unsigned int uint32;

// ---------------------------------------------------------------------------
// Workspace layout (ushort units): four bf16[256][256] arrays
//   [0]      Wn_hi[i][j] = hi(0.5*W[i][j])        (A-operand for Xv update)
//   [65536]  Wn_lo[i][j] = lo(0.5*W[i][j])
//   [131072] Wt_hi[j][i] = hi(0.5*W[i][j])        (A-operand for Xh update)
//   [196608] Wt_lo[j][i] = lo(0.5*W[i][j])
// ---------------------------------------------------------------------------

__global__ void HAM_prep_w(const float* __restrict__ W, unsigned short* __restrict__ ws)
{
    int idx = blockIdx.x * 256 + threadIdx.x;          // 0 .. 65535
    int i = idx >> 8, j = idx & 255;
    float w = 0.5f * W[idx];                           // fold alpha=0.5 into W
    uint32 u = __builtin_bit_cast(uint32, w);
    unsigned short hi = (unsigned short)(u >> 16);     // truncation split: lo captures remainder
    float fhi = __builtin_bit_cast(float, u & 0xFFFF0000u);
    float lo  = w - fhi;
    unsigned short lo16 = (unsigned short)(__builtin_bit_cast(uint32, lo) >> 16);
    ws[idx]              = hi;
    ws[65536  + idx]     = lo16;
    ws[131072 + j*256+i] = hi;
    ws[196608 + j*256+i] = lo16;
}

__device__ __forceinline__ float fast_tanh(float x)
{
    // tanh(x) = 1 - 2/(exp(2x)+1); exact at +-inf saturation, ~2ulp rel err
    float e = __expf(2.0f * x);
    return 1.0f - __fdividef(2.0f, e + 1.0f);
}

// ---------------------------------------------------------------------------
// Main kernel: 512 threads = 8 waves. Block handles 64 batch rows.
// Waves 0-3: own Xv^T feature strip [64w, 64w+64) x 64 batch (16 D-tiles 16x16)
// Waves 4-7: same for Xh^T.
// Per iteration:
//   1) g = tanh(x) from accumulators, split hi/lo bf16, write LDS [b][feat]
//      (XOR-swizzled), barrier
//   2) acc *= 0.5; acc += A(W from global, L2) * B(other-g from LDS)  via
//      3-product bf16 MFMA over K=256; barrier
// ---------------------------------------------------------------------------

__launch_bounds__(512, 2)
__global__ void HAM_main(const float* __restrict__ xv_in, const float* __restrict__ xh_in,
                         const unsigned short* __restrict__ wsp, const int* __restrict__ miter,
                         float* __restrict__ out)
{
    extern __shared__ char smem[];   // 128 KiB: gv_hi|gv_lo|gh_hi|gh_lo, 32 KiB each
    const int tid  = threadIdx.x;
    const int wid  = tid >> 6;
    const int lane = tid & 63;
    const int li   = lane & 15;      // MFMA n-col within tile (= batch within 16)
    const int g    = lane >> 4;      // quarter-wave group
    const bool isV = (wid < 4);
    const int fbase = (wid & 3) * 64;
    const long b0 = (long)blockIdx.x * 64;

    const float* xin = isV ? xv_in : xh_in;
    const unsigned short* aHiP = wsp + (isV ? 0     : 131072);
    const unsigned short* aLoP = wsp + (isV ? 65536 : 196608);
    char* gWr = smem + (isV ? 0 : 65536);   // where my wave's g goes
    char* gRd = smem + (isV ? 65536 : 0);   // the g my GEMM consumes

    // ---- load initial state into accumulators (D-layout) ----
    f32x4 acc[4][4];
    #pragma unroll
    for (int mt = 0; mt < 4; ++mt)
        #pragma unroll
        for (int nt = 0; nt < 4; ++nt) {
            long b = b0 + nt*16 + li;
            int  f = fbase + mt*16 + g*4;
            acc[mt][nt] = *(const f32x4*)(xin + b*256 + f);
        }

    const int iters = *miter;

    for (int it = 0; it < iters; ++it) {
        // ---- phase 1: g = tanh(x), split, write LDS ----
        #pragma unroll
        for (int mt = 0; mt < 4; ++mt) {
            #pragma unroll
            for (int nt = 0; nt < 4; ++nt) {
                int b   = nt*16 + li;
                int off = (b*512 + (fbase + mt*16 + g*4)*2) ^ ((b & 7) << 4);
                uint32 hv[4]; float lo[4];
                #pragma unroll
                for (int j = 0; j < 4; ++j) {
                    float t = fast_tanh(acc[mt][nt][j]);
                    uint32 u = __builtin_bit_cast(uint32, t);
                    hv[j] = u & 0xFFFF0000u;
                    lo[j] = t - __builtin_bit_cast(float, hv[j]);
                }
                uint32 h01 = (hv[0] >> 16) | hv[1];
                uint32 h23 = (hv[2] >> 16) | hv[3];
                uint32 l01 = (__builtin_bit_cast(uint32, lo[0]) >> 16) |
                             (__builtin_bit_cast(uint32, lo[1]) & 0xFFFF0000u);
                uint32 l23 = (__builtin_bit_cast(uint32, lo[2]) >> 16) |
                             (__builtin_bit_cast(uint32, lo[3]) & 0xFFFF0000u);
                *(uint2*)(gWr + off)         = make_uint2(h01, h23);
                *(uint2*)(gWr + 32768 + off) = make_uint2(l01, l23);
            }
        }
        __syncthreads();

        // ---- phase 2: x_new = 0.5*x + g_other * (0.5*W_sel) ----
        #pragma unroll
        for (int mt = 0; mt < 4; ++mt)
            #pragma unroll
            for (int nt = 0; nt < 4; ++nt)
                acc[mt][nt] *= 0.5f;

        #pragma unroll
        for (int kt = 0; kt < 8; ++kt) {
            const int k = kt*32 + g*8;
            s16x8 aHi[4], aLo[4], bHi[4], bLo[4];
            #pragma unroll
            for (int mt = 0; mt < 4; ++mt) {
                int m = fbase + mt*16 + li;
                aHi[mt] = *(const s16x8*)(aHiP + m*256 + k);
                aLo[mt] = *(const s16x8*)(aLoP + m*256 + k);
            }
            #pragma unroll
            for (int nt = 0; nt < 4; ++nt) {
                int b   = nt*16 + li;
                int off = (b*512 + k*2) ^ ((b & 7) << 4);
                bHi[nt] = *(const s16x8*)(gRd + off);
                bLo[nt] = *(const s16x8*)(gRd + 32768 + off);
            }
            #pragma unroll
            for (int mt = 0; mt < 4; ++mt)
                #pragma unroll
                for (int nt = 0; nt < 4; ++nt) {
                    acc[mt][nt] = __builtin_amdgcn_mfma_f32_16x16x32_bf16(aHi[mt], bHi[nt], acc[mt][nt], 0, 0, 0);
                    acc[mt][nt] = __builtin_amdgcn_mfma_f32_16x16x32_bf16(aLo[mt], bHi[nt], acc[mt][nt], 0, 0, 0);
                    acc[mt][nt] = __builtin_amdgcn_mfma_f32_16x16x32_bf16(aHi[mt], bLo[nt], acc[mt][nt], 0, 0, 0);
                }
        }
        __syncthreads();
    }

    // ---- epilogue: out[b] = [tanh(xv), tanh(xh)] ----
    const int colBase = (isV ? 0 : 256) + fbase;
    #pragma unroll
    for (int mt = 0; mt < 4; ++mt) {
        #pragma unroll
        for (int nt = 0; nt < 4; ++nt) {
            long b = b0 + nt*16 + li;
            f32x4 o;
            #pragma unroll
            for (int j = 0; j < 4; ++j) o[j] = fast_tanh(acc[mt][nt][j]);
            *(f32x4*)(out + b*512 + colBase + mt*16 + g*4) = o;
        }
    }
}

extern "C" void kernel_launch(void* const* d_in, const int* in_sizes, int n_in,
                              void* d_out, int out_size, void* d_ws, size_t ws_size,
                              hipStream_t stream)
{
    const float* xv   = (const float*)d_in[0];
    const float* xh   = (const float*)d_in[1];
    const float* W    = (const float*)d_in[2];
    const int* miter  = (const int*)d_in[3];
    float* out        = (float*)d_out;
    unsigned short* ws = (unsigned short*)d_ws;

    const int B = in_sizes[0] / 256;        // 32768

    HAM_prep_w<<<256, 256, 0, stream>>>(W, ws);

    (void)hipFuncSetAttribute((const void*)HAM_main,
                              hipFuncAttributeMaxDynamicSharedMemorySize, 131072);
    HAM_main<<<B / 64, 512, 131072, stream>>>(xv, xh, ws, miter, out);
}

// Round 3
// 462.461 us; speedup vs baseline: 1.0214x; 1.0214x over previous
//
#include <hip/hip_runtime.h>
#include <cstdint>

typedef float  f32x4 __attribute__((ext_vector_type(4)));
typedef short  s16x8 __attribute__((ext_vector_type(8)));
typedef unsigned int uint32;

// ---------------------------------------------------------------------------
// Workspace layout (ushort units): four bf16[256][256] arrays
//   [0]      Wn_hi[i][j] = hi(0.5*W[i][j])        (A-operand for Xv update)
//   [65536]  Wn_lo[i][j] = lo(0.5*W[i][j])
//   [131072] Wt_hi[j][i] = hi(0.5*W[i][j])        (A-operand for Xh update)
//   [196608] Wt_lo[j][i] = lo(0.5*W[i][j])
// ---------------------------------------------------------------------------

__global__ void HAM_prep_w(const float* __restrict__ W, unsigned short* __restrict__ ws)
{
    int idx = blockIdx.x * 256 + threadIdx.x;          // 0 .. 65535
    int i = idx >> 8, j = idx & 255;
    float w = 0.5f * W[idx];                           // fold alpha=0.5 into W
    uint32 u = __builtin_bit_cast(uint32, w);
    unsigned short hi = (unsigned short)(u >> 16);     // truncation split
    float fhi = __builtin_bit_cast(float, u & 0xFFFF0000u);
    float lo  = w - fhi;
    unsigned short lo16 = (unsigned short)(__builtin_bit_cast(uint32, lo) >> 16);
    ws[idx]              = hi;
    ws[65536  + idx]     = lo16;
    ws[131072 + j*256+i] = hi;
    ws[196608 + j*256+i] = lo16;
}

__device__ __forceinline__ float fast_tanh(float x)
{
    float e = __expf(2.0f * x);
    return 1.0f - __fdividef(2.0f, e + 1.0f);
}

// ---------------------------------------------------------------------------
// 512 threads = 8 waves; block owns 64 batch rows.
// Waves 0-3: Xv feature strips; waves 4-7: Xh feature strips.
// aHi (W hi-split, this wave's 64-feat strip) lives in 128 VGPRs across all
// iterations; aLo streamed from L2 with 1-kt-ahead prefetch.
// All W-fragment offsets are in USHORT units: chunk kt of a row = rp + kt*32.
// LDS g buffers swizzled with XOR (b&15)<<4 -> conflict-free b64 writes and
// b128 reads (16 distinct 16B slots per 16-lane group).
// ---------------------------------------------------------------------------

__launch_bounds__(512, 2)
__global__ void HAM_main(const float* __restrict__ xv_in, const float* __restrict__ xh_in,
                         const unsigned short* __restrict__ wsp, const int* __restrict__ miter,
                         float* __restrict__ out)
{
    extern __shared__ char smem[];   // 128 KiB: gv_hi|gv_lo|gh_hi|gh_lo, 32 KiB each
    const int tid  = threadIdx.x;
    const int wid  = tid >> 6;
    const int lane = tid & 63;
    const int li   = lane & 15;      // MFMA m/n index within tile
    const int g    = lane >> 4;      // quarter-wave group (k-chunk)
    const bool isV = (wid < 4);
    const int fbase = (wid & 3) * 64;
    const long b0 = (long)blockIdx.x * 64;

    const float* xin = isV ? xv_in : xh_in;
    const unsigned short* aHiP = wsp + (isV ? 0     : 131072);
    const unsigned short* aLoP = wsp + (isV ? 65536 : 196608);
    char* gWr = smem + (isV ? 0 : 65536);   // where my wave's g goes
    char* gRd = smem + (isV ? 65536 : 0);   // the g my GEMM consumes

    // ---- preload aHi fragments into registers (128 VGPRs, reused 10 iters) ----
    s16x8 aHi[4][8];
    const unsigned short* aLoRow[4];        // ushort pointers; chunk kt at +kt*32
    #pragma unroll
    for (int mt = 0; mt < 4; ++mt) {
        const unsigned short* rp = aHiP + (fbase + mt*16 + li)*256 + g*8;
        #pragma unroll
        for (int kt = 0; kt < 8; ++kt)
            aHi[mt][kt] = *(const s16x8*)(rp + kt*32);
        aLoRow[mt] = aLoP + (fbase + mt*16 + li)*256 + g*8;
    }

    // ---- load initial state into accumulators (D-layout) ----
    f32x4 acc[4][4];
    #pragma unroll
    for (int mt = 0; mt < 4; ++mt)
        #pragma unroll
        for (int nt = 0; nt < 4; ++nt) {
            long b = b0 + nt*16 + li;
            int  f = fbase + mt*16 + g*4;
            acc[mt][nt] = *(const f32x4*)(xin + b*256 + f);
        }

    const int iters = *miter;

    for (int it = 0; it < iters; ++it) {
        // ---- phase 1: g = tanh(x), split hi/lo bf16, write LDS ----
        #pragma unroll
        for (int mt = 0; mt < 4; ++mt) {
            #pragma unroll
            for (int nt = 0; nt < 4; ++nt) {
                int b   = nt*16 + li;
                int off = (b*512 + (fbase + mt*16 + g*4)*2) ^ ((b & 15) << 4);
                uint32 hv[4]; float lo[4];
                #pragma unroll
                for (int j = 0; j < 4; ++j) {
                    float t = fast_tanh(acc[mt][nt][j]);
                    uint32 u = __builtin_bit_cast(uint32, t);
                    hv[j] = u & 0xFFFF0000u;
                    lo[j] = t - __builtin_bit_cast(float, hv[j]);
                }
                uint32 h01 = (hv[0] >> 16) | hv[1];
                uint32 h23 = (hv[2] >> 16) | hv[3];
                uint32 l01 = (__builtin_bit_cast(uint32, lo[0]) >> 16) |
                             (__builtin_bit_cast(uint32, lo[1]) & 0xFFFF0000u);
                uint32 l23 = (__builtin_bit_cast(uint32, lo[2]) >> 16) |
                             (__builtin_bit_cast(uint32, lo[3]) & 0xFFFF0000u);
                *(uint2*)(gWr + off)         = make_uint2(h01, h23);
                *(uint2*)(gWr + 32768 + off) = make_uint2(l01, l23);
            }
        }
        __syncthreads();

        // ---- phase 2: x_new = 0.5*x + g_other * (0.5*W_sel) ----
        #pragma unroll
        for (int mt = 0; mt < 4; ++mt)
            #pragma unroll
            for (int nt = 0; nt < 4; ++nt)
                acc[mt][nt] *= 0.5f;

        s16x8 aLo[2][4];
        #pragma unroll
        for (int mt = 0; mt < 4; ++mt) aLo[0][mt] = *(const s16x8*)(aLoRow[mt]);

        #pragma unroll
        for (int kt = 0; kt < 8; ++kt) {
            if (kt < 7) {
                #pragma unroll
                for (int mt = 0; mt < 4; ++mt)
                    aLo[(kt + 1) & 1][mt] = *(const s16x8*)(aLoRow[mt] + (kt + 1) * 32);
            }
            #pragma unroll
            for (int nt = 0; nt < 4; ++nt) {
                int b   = nt*16 + li;
                int off = (b*512 + kt*64 + g*16) ^ ((b & 15) << 4);
                s16x8 bHi = *(const s16x8*)(gRd + off);
                s16x8 bLo = *(const s16x8*)(gRd + 32768 + off);
                #pragma unroll
                for (int mt = 0; mt < 4; ++mt) {
                    acc[mt][nt] = __builtin_amdgcn_mfma_f32_16x16x32_bf16(aHi[mt][kt], bHi, acc[mt][nt], 0, 0, 0);
                    acc[mt][nt] = __builtin_amdgcn_mfma_f32_16x16x32_bf16(aHi[mt][kt], bLo, acc[mt][nt], 0, 0, 0);
                    acc[mt][nt] = __builtin_amdgcn_mfma_f32_16x16x32_bf16(aLo[kt & 1][mt], bHi, acc[mt][nt], 0, 0, 0);
                }
            }
        }
        __syncthreads();
    }

    // ---- epilogue: out[b] = [tanh(xv), tanh(xh)] ----
    const int colBase = (isV ? 0 : 256) + fbase;
    #pragma unroll
    for (int mt = 0; mt < 4; ++mt) {
        #pragma unroll
        for (int nt = 0; nt < 4; ++nt) {
            long b = b0 + nt*16 + li;
            f32x4 o;
            #pragma unroll
            for (int j = 0; j < 4; ++j) o[j] = fast_tanh(acc[mt][nt][j]);
            *(f32x4*)(out + b*512 + colBase + mt*16 + g*4) = o;
        }
    }
}

extern "C" void kernel_launch(void* const* d_in, const int* in_sizes, int n_in,
                              void* d_out, int out_size, void* d_ws, size_t ws_size,
                              hipStream_t stream)
{
    const float* xv   = (const float*)d_in[0];
    const float* xh   = (const float*)d_in[1];
    const float* W    = (const float*)d_in[2];
    const int* miter  = (const int*)d_in[3];
    float* out        = (float*)d_out;
    unsigned short* ws = (unsigned short*)d_ws;

    const int B = in_sizes[0] / 256;        // 32768

    HAM_prep_w<<<256, 256, 0, stream>>>(W, ws);

    (void)hipFuncSetAttribute((const void*)HAM_main,
                              hipFuncAttributeMaxDynamicSharedMemorySize, 131072);
    HAM_main<<<B / 64, 512, 131072, stream>>>(xv, xh, ws, miter, out);
}

// Round 5
// 165.140 us; speedup vs baseline: 2.8605x; 2.8004x over previous
//
#include <hip/hip_runtime.h>
#include <cstdint>

typedef float    f32x4 __attribute__((ext_vector_type(4)));
typedef _Float16 f16x8 __attribute__((ext_vector_type(8)));
typedef unsigned int uint32;

// ---------------------------------------------------------------------------
// Workspace (ushort units): two fp16[256][256] arrays (RNE, alpha folded in)
//   [0]      Wn[i][j] = f16(0.5*W[i][j])   (A-operand for Xv update)
//   [65536]  Wt[j][i] = f16(0.5*W[i][j])   (A-operand for Xh update)
// ---------------------------------------------------------------------------

__global__ void HAM_prep_w(const float* __restrict__ W, unsigned short* __restrict__ ws)
{
    int idx = blockIdx.x * 256 + threadIdx.x;          // 0 .. 65535
    int i = idx >> 8, j = idx & 255;
    _Float16 h = (_Float16)(0.5f * W[idx]);            // RNE, rel err <= 2^-12
    unsigned short hb = __builtin_bit_cast(unsigned short, h);
    ws[idx] = hb;
    ws[65536 + j*256 + i] = hb;
}

__device__ __forceinline__ float fast_tanh(float x)
{
    float e = __expf(2.0f * x);
    return 1.0f - __fdividef(2.0f, e + 1.0f);
}

// ---------------------------------------------------------------------------
// 512 threads = 8 waves; block owns 64 batch rows. Waves 0-3: Xv 64-feat
// strips; waves 4-7: Xh. W (fp16) strip lives in 128 VGPRs for all
// iterations; NO global loads inside the iteration loop.
// g (fp16) double-buffered in LDS (2 x 64 KiB) -> ONE barrier per iteration:
//   phase1: write g[it&1] (own strip) | barrier | phase2: read g[it&1] (other)
// Race-free: a wave in phase1(it+1) writes buf[(it+1)&1]; the slowest wave
// still in phase2(it) reads buf[it&1] — different buffers.
// Swizzle: XOR (li<<4) applied to the FULL byte offset (round-3 form,
// bijective within each 512B row; preserves 8B/16B alignment).
// ---------------------------------------------------------------------------

__launch_bounds__(512, 2)
__global__ void HAM_main(const float* __restrict__ xv_in, const float* __restrict__ xh_in,
                         const unsigned short* __restrict__ wsp, const int* __restrict__ miter,
                         float* __restrict__ out)
{
    extern __shared__ char smem[];   // 128 KiB: buf0{gv|gh} buf1{gv|gh}, 32 KiB halves
    const int tid  = threadIdx.x;
    const int wid  = tid >> 6;
    const int lane = tid & 63;
    const int li   = lane & 15;      // MFMA m/n index within tile
    const int g    = lane >> 4;      // quarter-wave group (k-chunk)
    const bool isV = (wid < 4);
    const int fbase = (wid & 3) * 64;
    const long b0 = (long)blockIdx.x * 64;

    const float* xin = isV ? xv_in : xh_in;
    const unsigned short* aP = wsp + (isV ? 0 : 65536);
    const int wrHalf = isV ? 0 : 32768;      // my g goes here (within a buffer)
    const int rdHalf = isV ? 32768 : 0;      // my GEMM consumes the other half

    // ---- preload W strip into registers (128 VGPRs, reused every iter) ----
    f16x8 aW[4][8];
    #pragma unroll
    for (int mt = 0; mt < 4; ++mt) {
        const unsigned short* rp = aP + (fbase + mt*16 + li)*256 + g*8;
        #pragma unroll
        for (int kt = 0; kt < 8; ++kt)
            aW[mt][kt] = *(const f16x8*)(rp + kt*32);   // ushort-unit offsets
    }

    // ---- load initial state into accumulators (D-layout) ----
    f32x4 acc[4][4];
    #pragma unroll
    for (int mt = 0; mt < 4; ++mt)
        #pragma unroll
        for (int nt = 0; nt < 4; ++nt) {
            long b = b0 + nt*16 + li;
            int  f = fbase + mt*16 + g*4;
            acc[mt][nt] = *(const f32x4*)(xin + b*256 + f);
        }

    const int iters = *miter;

    for (int it = 0; it < iters; ++it) {
        char* buf = smem + (it & 1) * 65536;
        char* wr  = buf + wrHalf;
        char* rd  = buf + rdHalf;

        // ---- phase 1: g = tanh(x) -> fp16 pairs -> LDS ----
        #pragma unroll
        for (int mt = 0; mt < 4; ++mt) {
            #pragma unroll
            for (int nt = 0; nt < 4; ++nt) {
                float t0 = fast_tanh(acc[mt][nt][0]);
                float t1 = fast_tanh(acc[mt][nt][1]);
                float t2 = fast_tanh(acc[mt][nt][2]);
                float t3 = fast_tanh(acc[mt][nt][3]);
                uint32 u01 = (uint32)__builtin_bit_cast(unsigned short, (_Float16)t0)
                           | ((uint32)__builtin_bit_cast(unsigned short, (_Float16)t1) << 16);
                uint32 u23 = (uint32)__builtin_bit_cast(unsigned short, (_Float16)t2)
                           | ((uint32)__builtin_bit_cast(unsigned short, (_Float16)t3) << 16);
                int off = (((nt*16 + li) * 512) + (fbase + mt*16 + g*4) * 2) ^ (li << 4);
                *(uint2*)(wr + off) = make_uint2(u01, u23);
            }
        }
        __syncthreads();

        // ---- phase 2: x_new = 0.5*x + g_other * (0.5*W) ----
        #pragma unroll
        for (int mt = 0; mt < 4; ++mt)
            #pragma unroll
            for (int nt = 0; nt < 4; ++nt)
                acc[mt][nt] *= 0.5f;

        #pragma unroll
        for (int kt = 0; kt < 8; ++kt) {
            #pragma unroll
            for (int nt = 0; nt < 4; ++nt) {
                int off = (((nt*16 + li) * 512) + kt*64 + g*16) ^ (li << 4);
                f16x8 bH = *(const f16x8*)(rd + off);
                #pragma unroll
                for (int mt = 0; mt < 4; ++mt)
                    acc[mt][nt] = __builtin_amdgcn_mfma_f32_16x16x32_f16(aW[mt][kt], bH, acc[mt][nt], 0, 0, 0);
            }
        }
        // no trailing barrier: next phase-1 writes the OTHER buffer
    }

    // ---- epilogue: out[b] = [tanh(xv), tanh(xh)] ----
    const int colBase = (isV ? 0 : 256) + fbase;
    #pragma unroll
    for (int mt = 0; mt < 4; ++mt) {
        #pragma unroll
        for (int nt = 0; nt < 4; ++nt) {
            long b = b0 + nt*16 + li;
            f32x4 o;
            #pragma unroll
            for (int j = 0; j < 4; ++j) o[j] = fast_tanh(acc[mt][nt][j]);
            *(f32x4*)(out + b*512 + colBase + mt*16 + g*4) = o;
        }
    }
}

extern "C" void kernel_launch(void* const* d_in, const int* in_sizes, int n_in,
                              void* d_out, int out_size, void* d_ws, size_t ws_size,
                              hipStream_t stream)
{
    const float* xv   = (const float*)d_in[0];
    const float* xh   = (const float*)d_in[1];
    const float* W    = (const float*)d_in[2];
    const int* miter  = (const int*)d_in[3];
    float* out        = (float*)d_out;
    unsigned short* ws = (unsigned short*)d_ws;

    const int B = in_sizes[0] / 256;        // 32768

    HAM_prep_w<<<256, 256, 0, stream>>>(W, ws);

    (void)hipFuncSetAttribute((const void*)HAM_main,
                              hipFuncAttributeMaxDynamicSharedMemorySize, 131072);
    HAM_main<<<B / 64, 512, 131072, stream>>>(xv, xh, ws, miter, out);
}